// Round 8
// baseline (157.720 us; speedup 1.0000x reference)
//
#include <hip/hip_runtime.h>

#define NUM_CLASSES 64
#define GRID 1250   // n = 2,000,000 = 1250 blocks x 25 slabs x 64 rows exactly

typedef float f32x4 __attribute__((ext_vector_type(4)));

// Fused: exp column sums + target histogram + NLL pick + last-block finalize.
// 16 lanes per row (lane c16 owns cols 4*c16..), wave covers 4 consecutive
// rows per load instr = 1KB contiguous. 4 independent row loads in flight.
// PLAIN loads (no nt): let the 256MB Infinity Cache retain pred across
// graph replays. Finalize: acq-rel ticket, NO per-block threadfence (R4's
// 5x regression was the 2048 L2-flush fences, not the ticket).
__global__ __launch_bounds__(256) void loss_fused(
    const float* __restrict__ pred,      // [n][64]
    const int* __restrict__ tgt,         // [n]
    float* __restrict__ g_colsum,        // ws+0    [64] f32 (zeroed)
    unsigned int* __restrict__ g_cnt,    // ws+256  [64] u32 (zeroed)
    float* __restrict__ g_nll,           // ws+512  f32     (zeroed)
    unsigned int* __restrict__ ticket,   // ws+516  u32     (zeroed)
    float* __restrict__ out,             // [1]
    int n)
{
    __shared__ float s_col[NUM_CLASSES];
    __shared__ unsigned int s_cnt[NUM_CLASSES];
    __shared__ float s_nll[4];
    __shared__ int s_last;

    const int t = threadIdx.x;
    if (t < NUM_CLASSES) { s_col[t] = 0.f; s_cnt[t] = 0u; }
    __syncthreads();

    const int c16  = t & 15;          // column quad
    const int rloc = t >> 4;          // row slot within 16-row group
    const int c0   = c16 * 4;

    // balanced slab ranges: exactly 25 full slabs/block for n=2M, G=1250
    const long slabs = (n + 63) >> 6;
    const long s0 = (long)blockIdx.x * slabs / GRID;
    const long s1 = (long)(blockIdx.x + 1) * slabs / GRID;

    float ca0 = 0.f, ca1 = 0.f, ca2 = 0.f, ca3 = 0.f;
    float nllacc = 0.f;

    for (long s = s0; s < s1; ++s) {
        const long base = s << 6;
        if (base + 64 <= n) {           // full slab (always when 64 | n)
            f32x4 v[4];
            int   tg[4];
            #pragma unroll
            for (int j = 0; j < 4; ++j) {   // issue all loads first (ILP)
                const long row = base + rloc + j * 16;
                v[j]  = *reinterpret_cast<const f32x4*>(pred + row * NUM_CLASSES + c0);
                tg[j] = tgt[row];           // L1 broadcast across 16 lanes
            }
            #pragma unroll
            for (int j = 0; j < 4; ++j) {
                ca0 += __expf(v[j][0]);
                ca1 += __expf(v[j][1]);
                ca2 += __expf(v[j][2]);
                ca3 += __expf(v[j][3]);
                if (c16 == j) atomicAdd(&s_cnt[tg[j]], 1u);  // spread hist atomics
                const int d = tg[j] - c0;
                if ((unsigned)d < 4u)
                    nllacc += (d==0)?v[j][0]:(d==1)?v[j][1]:(d==2)?v[j][2]:v[j][3];
            }
        } else {                        // masked last slab (n % 64 != 0 only)
            #pragma unroll
            for (int j = 0; j < 4; ++j) {
                const long row = base + rloc + j * 16;
                if (row < n) {
                    const f32x4 w = *reinterpret_cast<const f32x4*>(pred + row * NUM_CLASSES + c0);
                    const int g = tgt[row];
                    ca0 += __expf(w[0]); ca1 += __expf(w[1]);
                    ca2 += __expf(w[2]); ca3 += __expf(w[3]);
                    if (c16 == j) atomicAdd(&s_cnt[g], 1u);
                    const int d = g - c0;
                    if ((unsigned)d < 4u) nllacc += (d==0)?w[0]:(d==1)?w[1]:(d==2)?w[2]:w[3];
                }
            }
        }
    }

    // block reduction
    atomicAdd(&s_col[c0 + 0], ca0);
    atomicAdd(&s_col[c0 + 1], ca1);
    atomicAdd(&s_col[c0 + 2], ca2);
    atomicAdd(&s_col[c0 + 3], ca3);

    for (int off = 32; off; off >>= 1) nllacc += __shfl_down(nllacc, off);
    if ((t & 63) == 0) s_nll[t >> 6] = nllacc;
    __syncthreads();

    // device-scope atomic accumulation (66 atomics/block; R2/R7-proven)
    if (t == 0) atomicAdd(g_nll, s_nll[0] + s_nll[1] + s_nll[2] + s_nll[3]);
    if (t < NUM_CLASSES) {
        atomicAdd(&g_colsum[t], s_col[t]);
        atomicAdd(&g_cnt[t], s_cnt[t]);
    }

    // last-arriving block finalizes. Release on ticket orders our atomics;
    // acquire lets the last block see everyone's. No threadfence.
    if (t == 0) {
        const unsigned old = __hip_atomic_fetch_add(ticket, 1u, __ATOMIC_ACQ_REL,
                                                    __HIP_MEMORY_SCOPE_AGENT);
        s_last = (old == (unsigned)(GRID - 1));
    }
    __syncthreads();

    if (s_last && t < NUM_CLASSES) {
        const float    cs  = __hip_atomic_load(&g_colsum[t], __ATOMIC_RELAXED, __HIP_MEMORY_SCOPE_AGENT);
        const unsigned cn  = __hip_atomic_load(&g_cnt[t],    __ATOMIC_RELAXED, __HIP_MEMORY_SCOPE_AGENT);
        const float    nll = __hip_atomic_load(g_nll,        __ATOMIC_RELAXED, __HIP_MEMORY_SCOPE_AGENT);
        const float diff = (float)cn - cs;
        float p = diff * diff;
        for (int off = 32; off; off >>= 1) p += __shfl_down(p, off);
        if (t == 0) out[0] = (p - nll) / (float)n;
    }
}

extern "C" void kernel_launch(void* const* d_in, const int* in_sizes, int n_in,
                              void* d_out, int out_size, void* d_ws, size_t ws_size,
                              hipStream_t stream)
{
    const float* pred = (const float*)d_in[0];
    const int* tgt    = (const int*)d_in[1];
    const int n       = in_sizes[1];

    float*        g_colsum = (float*)d_ws;
    unsigned int* g_cnt    = (unsigned int*)((char*)d_ws + 256);
    float*        g_nll    = (float*)((char*)d_ws + 512);
    unsigned int* ticket   = (unsigned int*)((char*)d_ws + 516);

    (void)hipMemsetAsync(d_ws, 0, 1024, stream);  // zero accumulators + ticket

    loss_fused<<<GRID, 256, 0, stream>>>(pred, tgt, g_colsum, g_cnt, g_nll,
                                         ticket, (float*)d_out, n);
}

// Round 9
// 102.479 us; speedup vs baseline: 1.5390x; 1.5390x over previous
//
#include <hip/hip_runtime.h>

#define NUM_CLASSES 64
#define GRID 2048

typedef float f32x4 __attribute__((ext_vector_type(4)));

// Pass 1: exp column sums + target histogram + NLL pick.
// R2/R7-proven hot loop (nt pred loads, scalar L1-broadcast tgt loads,
// spread LDS hist atomics) + NEW: 2-deep software pipeline — slab s+1's
// loads are issued before slab s is consumed, doubling in-flight VMEM.
__global__ __launch_bounds__(256) void loss_pass1(
    const float* __restrict__ pred,      // [n][64]
    const int* __restrict__ tgt,         // [n]
    float* __restrict__ g_colsum,        // [64]  (zeroed by memset)
    unsigned int* __restrict__ g_cnt,    // [64]  (zeroed)
    float* __restrict__ g_nll,           // [1]   (zeroed)
    int n)
{
    __shared__ float s_col[NUM_CLASSES];
    __shared__ unsigned int s_cnt[NUM_CLASSES];
    __shared__ float s_nll[4];

    const int t = threadIdx.x;
    if (t < NUM_CLASSES) { s_col[t] = 0.f; s_cnt[t] = 0u; }
    __syncthreads();

    const int c16  = t & 15;          // column quad (cols 4*c16..4*c16+3)
    const int rloc = t >> 4;          // row slot within 16-row group
    const int c0   = c16 * 4;

    // full 64-row slabs only; balanced ranges (15 or 16 slabs/block @2048)
    const long slabs = (long)n >> 6;
    const long s0 = (long)blockIdx.x * slabs / GRID;
    const long s1 = (long)(blockIdx.x + 1) * slabs / GRID;

    float ca0 = 0.f, ca1 = 0.f, ca2 = 0.f, ca3 = 0.f;
    float nllacc = 0.f;

    f32x4 va[4], vb[4];
    int   ta[4], tb[4];

    auto load = [&](f32x4* v, int* tg, long s) {
        const long base = s << 6;
        #pragma unroll
        for (int j = 0; j < 4; ++j) {
            const long row = base + rloc + j * 16;
            v[j]  = __builtin_nontemporal_load(
                      reinterpret_cast<const f32x4*>(pred + row * NUM_CLASSES + c0));
            tg[j] = tgt[row];
        }
    };
    auto consume = [&](const f32x4* v, const int* tg) {
        #pragma unroll
        for (int j = 0; j < 4; ++j) {
            ca0 += __expf(v[j][0]);
            ca1 += __expf(v[j][1]);
            ca2 += __expf(v[j][2]);
            ca3 += __expf(v[j][3]);
            if (c16 == j) atomicAdd(&s_cnt[tg[j]], 1u);
            const int d = tg[j] - c0;
            if ((unsigned)d < 4u)
                nllacc += (d==0)?v[j][0]:(d==1)?v[j][1]:(d==2)?v[j][2]:v[j][3];
        }
    };

    if (s0 < s1) {
        long s = s0;
        load(va, ta, s);
        while (true) {   // 2-deep pipeline, statically-named buffers (no scratch)
            if (s + 1 < s1) { load(vb, tb, s + 1); consume(va, ta); ++s; }
            else            { consume(va, ta); break; }
            if (s + 1 < s1) { load(va, ta, s + 1); consume(vb, tb); ++s; }
            else            { consume(vb, tb); break; }
        }
    }

    // partial last slab (only if 64 does not divide n), last block handles it
    if (blockIdx.x == GRID - 1 && (n & 63)) {
        const long base = slabs << 6;
        #pragma unroll
        for (int j = 0; j < 4; ++j) {
            const long row = base + rloc + j * 16;
            if (row < n) {
                const f32x4 w = *reinterpret_cast<const f32x4*>(pred + row * NUM_CLASSES + c0);
                const int g = tgt[row];
                ca0 += __expf(w[0]); ca1 += __expf(w[1]);
                ca2 += __expf(w[2]); ca3 += __expf(w[3]);
                if (c16 == j) atomicAdd(&s_cnt[g], 1u);
                const int d = g - c0;
                if ((unsigned)d < 4u) nllacc += (d==0)?w[0]:(d==1)?w[1]:(d==2)?w[2]:w[3];
            }
        }
    }

    // block reduction
    atomicAdd(&s_col[c0 + 0], ca0);
    atomicAdd(&s_col[c0 + 1], ca1);
    atomicAdd(&s_col[c0 + 2], ca2);
    atomicAdd(&s_col[c0 + 3], ca3);

    for (int off = 32; off; off >>= 1) nllacc += __shfl_down(nllacc, off);
    if ((t & 63) == 0) s_nll[t >> 6] = nllacc;
    __syncthreads();

    // device-scope atomic accumulation (66 atomics/block; R2/R7-proven)
    if (t == 0) atomicAdd(g_nll, s_nll[0] + s_nll[1] + s_nll[2] + s_nll[3]);
    if (t < NUM_CLASSES) {
        atomicAdd(&g_colsum[t], s_col[t]);
        atomicAdd(&g_cnt[t], s_cnt[t]);
    }
}

// Finalize: 64 threads, reads 516B, writes the scalar.
__global__ void loss_finalize(const float* __restrict__ g_colsum,
                              const unsigned int* __restrict__ g_cnt,
                              const float* __restrict__ g_nll,
                              float* __restrict__ out, int n)
{
    const int t = threadIdx.x;
    const float diff = (float)g_cnt[t] - g_colsum[t];
    float p = diff * diff;
    for (int off = 32; off; off >>= 1) p += __shfl_down(p, off);
    if (t == 0) out[0] = (p - g_nll[0]) / (float)n;
}

extern "C" void kernel_launch(void* const* d_in, const int* in_sizes, int n_in,
                              void* d_out, int out_size, void* d_ws, size_t ws_size,
                              hipStream_t stream)
{
    const float* pred = (const float*)d_in[0];
    const int* tgt    = (const int*)d_in[1];
    const int n       = in_sizes[1];

    float*        g_colsum = (float*)d_ws;
    unsigned int* g_cnt    = (unsigned int*)((char*)d_ws + 256);
    float*        g_nll    = (float*)((char*)d_ws + 512);

    (void)hipMemsetAsync(d_ws, 0, 1024, stream);

    loss_pass1<<<GRID, 256, 0, stream>>>(pred, tgt, g_colsum, g_cnt, g_nll, n);
    loss_finalize<<<1, 64, 0, stream>>>(g_colsum, g_cnt, g_nll, (float*)d_out, n);
}

// Round 10
// 102.301 us; speedup vs baseline: 1.5417x; 1.0017x over previous
//
#include <hip/hip_runtime.h>

#define NUM_CLASSES 64
#define GRID 2048

typedef float f32x4 __attribute__((ext_vector_type(4)));

// Pass 1: exp column sums + target histogram + NLL pick.
// R9 structure (nt pred loads, 2-deep pipeline) + NEW: single target load
// per thread-slab (wave's 16 rows, 4-way redundant) + shfl routing.
// VMEM instrs per thread-slab: 8 -> 5.
__global__ __launch_bounds__(256) void loss_pass1(
    const float* __restrict__ pred,      // [n][64]
    const int* __restrict__ tgt,         // [n]
    float* __restrict__ g_colsum,        // [64]  (zeroed by memset)
    unsigned int* __restrict__ g_cnt,    // [64]  (zeroed)
    float* __restrict__ g_nll,           // [1]   (zeroed)
    int n)
{
    __shared__ float s_col[NUM_CLASSES];
    __shared__ unsigned int s_cnt[NUM_CLASSES];
    __shared__ float s_nll[4];

    const int t = threadIdx.x;
    if (t < NUM_CLASSES) { s_col[t] = 0.f; s_cnt[t] = 0u; }
    __syncthreads();

    const int c16  = t & 15;          // column quad (cols 4*c16..4*c16+3)
    const int rloc = t >> 4;          // row slot within 16-row group
    const int c0   = c16 * 4;
    const int w4   = (t >> 6) * 4;    // wave's base rloc (4w)
    const int r    = rloc & 3;        // row within wave's rloc group

    // full 64-row slabs, balanced ranges
    const long slabs = (long)n >> 6;
    const long s0 = (long)blockIdx.x * slabs / GRID;
    const long s1 = (long)(blockIdx.x + 1) * slabs / GRID;

    float ca0 = 0.f, ca1 = 0.f, ca2 = 0.f, ca3 = 0.f;
    float nllacc = 0.f;

    f32x4 va[4], vb[4];
    int   ta, tb;

    // lane c16 of each wave loads target row base + w4 + (c16&3) + (c16>>2)*16
    const int trow_off = w4 + (c16 & 3) + (c16 >> 2) * 16;

    auto load = [&](f32x4* v, int& traw, long s) {
        const long base = s << 6;
        #pragma unroll
        for (int j = 0; j < 4; ++j) {
            const long row = base + rloc + j * 16;
            v[j] = __builtin_nontemporal_load(
                     reinterpret_cast<const f32x4*>(pred + row * NUM_CLASSES + c0));
        }
        traw = tgt[base + trow_off];   // 1 VMEM instr, 16 unique rows per wave
    };
    auto consume = [&](const f32x4* v, int traw) {
        // histogram: the 16 lanes with (rloc&3)==0 each own one wave row
        if (r == 0) atomicAdd(&s_cnt[traw], 1u);
        #pragma unroll
        for (int j = 0; j < 4; ++j) {
            ca0 += __expf(v[j][0]);
            ca1 += __expf(v[j][1]);
            ca2 += __expf(v[j][2]);
            ca3 += __expf(v[j][3]);
            // my row (rloc + 16j) was loaded by wave lane r + 4j
            const int tg = __shfl(traw, r + 4 * j, 64);
            const int d = tg - c0;
            if ((unsigned)d < 4u)
                nllacc += (d==0)?v[j][0]:(d==1)?v[j][1]:(d==2)?v[j][2]:v[j][3];
        }
    };

    if (s0 < s1) {
        long s = s0;
        load(va, ta, s);
        while (true) {   // 2-deep pipeline, statically-named buffers
            if (s + 1 < s1) { load(vb, tb, s + 1); consume(va, ta); ++s; }
            else            { consume(va, ta); break; }
            if (s + 1 < s1) { load(va, ta, s + 1); consume(vb, tb); ++s; }
            else            { consume(vb, tb); break; }
        }
    }

    // partial last slab (only if 64 does not divide n), last block handles it
    if (blockIdx.x == GRID - 1 && (n & 63)) {
        const long base = slabs << 6;
        #pragma unroll
        for (int j = 0; j < 4; ++j) {
            const long row = base + rloc + j * 16;
            if (row < n) {
                const f32x4 wv = *reinterpret_cast<const f32x4*>(pred + row * NUM_CLASSES + c0);
                const int g = tgt[row];
                ca0 += __expf(wv[0]); ca1 += __expf(wv[1]);
                ca2 += __expf(wv[2]); ca3 += __expf(wv[3]);
                if (c16 == j) atomicAdd(&s_cnt[g], 1u);
                const int d = g - c0;
                if ((unsigned)d < 4u) nllacc += (d==0)?wv[0]:(d==1)?wv[1]:(d==2)?wv[2]:wv[3];
            }
        }
    }

    // block reduction
    atomicAdd(&s_col[c0 + 0], ca0);
    atomicAdd(&s_col[c0 + 1], ca1);
    atomicAdd(&s_col[c0 + 2], ca2);
    atomicAdd(&s_col[c0 + 3], ca3);

    for (int off = 32; off; off >>= 1) nllacc += __shfl_down(nllacc, off);
    if ((t & 63) == 0) s_nll[t >> 6] = nllacc;
    __syncthreads();

    // device-scope atomic accumulation (66 atomics/block; proven)
    if (t == 0) atomicAdd(g_nll, s_nll[0] + s_nll[1] + s_nll[2] + s_nll[3]);
    if (t < NUM_CLASSES) {
        atomicAdd(&g_colsum[t], s_col[t]);
        atomicAdd(&g_cnt[t], s_cnt[t]);
    }
}

// Finalize: 64 threads, reads 516B, writes the scalar.
__global__ void loss_finalize(const float* __restrict__ g_colsum,
                              const unsigned int* __restrict__ g_cnt,
                              const float* __restrict__ g_nll,
                              float* __restrict__ out, int n)
{
    const int t = threadIdx.x;
    const float diff = (float)g_cnt[t] - g_colsum[t];
    float p = diff * diff;
    for (int off = 32; off; off >>= 1) p += __shfl_down(p, off);
    if (t == 0) out[0] = (p - g_nll[0]) / (float)n;
}

extern "C" void kernel_launch(void* const* d_in, const int* in_sizes, int n_in,
                              void* d_out, int out_size, void* d_ws, size_t ws_size,
                              hipStream_t stream)
{
    const float* pred = (const float*)d_in[0];
    const int* tgt    = (const int*)d_in[1];
    const int n       = in_sizes[1];

    float*        g_colsum = (float*)d_ws;
    unsigned int* g_cnt    = (unsigned int*)((char*)d_ws + 256);
    float*        g_nll    = (float*)((char*)d_ws + 512);

    (void)hipMemsetAsync(d_ws, 0, 1024, stream);

    loss_pass1<<<GRID, 256, 0, stream>>>(pred, tgt, g_colsum, g_cnt, g_nll, n);
    loss_finalize<<<1, 64, 0, stream>>>(g_colsum, g_cnt, g_nll, (float*)d_out, n);
}